// Round 3
// baseline (174.516 us; speedup 1.0000x reference)
//
#include <hip/hip_runtime.h>

typedef short short8 __attribute__((ext_vector_type(8)));
typedef float f32x16 __attribute__((ext_vector_type(16)));
typedef float f32x2 __attribute__((ext_vector_type(2)));
typedef unsigned int u32x2 __attribute__((ext_vector_type(2)));
typedef unsigned int u32x4 __attribute__((ext_vector_type(4)));

#define CHUNK_ELEMS 8192   // 8 ksteps * 1024 bf16 = 16 KB
#define HT_STRIDE 72

__device__ __forceinline__ unsigned short f2bf(float f) {
    unsigned int u = __float_as_uint(f);
    u += 0x7fffu + ((u >> 16) & 1u);
    return (unsigned short)(u >> 16);
}
__device__ __forceinline__ float bf2f(unsigned short h) {
    return __uint_as_float(((unsigned int)h) << 16);
}

// pack two f32 products -> bf16x2, round-half-away (bits + 0x8000), 1 v_perm pack
__device__ __forceinline__ unsigned int pk2bf_rhaz(f32x2 p) {
    u32x2 u = __builtin_bit_cast(u32x2, p);
    u += (u32x2){0x8000u, 0x8000u};
    return __builtin_amdgcn_perm(u.y, u.x, 0x07060302u); // [u0.b2,u0.b3,u1.b2,u1.b3]
}

// RNE pack (prepack path — W quality matters, cost is off the critical path)
__device__ __forceinline__ unsigned int pk2bf_rne(float lo, float hi) {
    unsigned int a = __float_as_uint(lo);
    a += 0x7fffu + ((a >> 16) & 1u);
    unsigned int b = __float_as_uint(hi);
    b += 0x7fffu + ((b >> 16) & 1u);
    return (a >> 16) | (b & 0xffff0000u);
}

// Repack W (fp32 [o][c], c=i*64+j) into bf16 A-fragment order for 32x32x16:
// Wf[l][ks(256)][ot(2)][lane(64)][t(8)] = bf16(W_l[ot*32+(lane&31)][ks*16+(lane>>5)*8+t])
__global__ __launch_bounds__(256) void prepack_kernel(const float* __restrict__ W1,
                                                      const float* __restrict__ W2,
                                                      unsigned short* __restrict__ Wf) {
    int tid = blockIdx.x * 256 + threadIdx.x; // 0..65535
    int cg = tid & 511;        // c = cg*8
    int o = (tid >> 9) & 63;
    int l = tid >> 15;
    const float* W = l ? W2 : W1;
    const float4* src = (const float4*)(W + o * 4096 + cg * 8);
    float4 v0 = src[0];
    float4 v1 = src[1];
    int ks = cg >> 1;
    int q2 = cg & 1;
    int lane = (q2 << 5) | (o & 31);
    int ot = o >> 5;
    u32x4 pv;
    pv[0] = pk2bf_rne(v0.x, v0.y);
    pv[1] = pk2bf_rne(v0.z, v0.w);
    pv[2] = pk2bf_rne(v1.x, v1.y);
    pv[3] = pk2bf_rne(v1.z, v1.w);
    ((u32x4*)Wf)[((l * 256 + ks) * 2 + ot) * 64 + lane] = pv;
}

// async stage of one 16 KB W-chunk across 4 waves
__device__ __forceinline__ void stage_chunk(const unsigned short* g, unsigned short* s,
                                            int w, int lane) {
#pragma unroll
    for (int r = 0; r < 4; ++r) {
        const unsigned short* gp = g + w * 2048 + r * 512 + lane * 8;
        unsigned short* lp = s + w * 2048 + r * 512;
        __builtin_amdgcn_global_load_lds(
            (const __attribute__((address_space(1))) unsigned int*)gp,
            (__attribute__((address_space(3))) unsigned int*)lp,
            16, 0, 0);
    }
}

// Block = 2 batch elems, 4 waves: wave w -> (ot = w>>1, dt = w&1), BOTH b's.
// Per kstep: 1 A-frag ds_read_b128 (shared across b's) + 2 B-builds + 2 MFMAs.
__global__ __launch_bounds__(256, 2) void cin_kernel(const float* __restrict__ x,
                                                     const unsigned short* __restrict__ Wf,
                                                     const float* __restrict__ b1,
                                                     const float* __restrict__ b2,
                                                     const float* __restrict__ Wfc,
                                                     const float* __restrict__ bfc,
                                                     float* __restrict__ out) {
    __shared__ __align__(16) unsigned short sW[2 * CHUNK_ELEMS];     // 32 KB dbuf
    __shared__ __align__(16) unsigned short sHT[2][64 * HT_STRIDE];  // 18.4 KB handoff
    __shared__ float sBias[128], sWfcS[128], sRed[4][2];

    const int tid = threadIdx.x;
    const int w = tid >> 6;
    const int lane = tid & 63;
    const int q2 = lane >> 5;
    const int n31 = lane & 31;
    const int ot = w >> 1;
    const int dt = w & 1;
    const int d = dt * 32 + n31;
    const int bb = blockIdx.x;
    const float* xb0 = x + bb * 2 * 4096;
    const float* xb1 = xb0 + 4096;

    if (tid < 64) {
        sBias[tid] = b1[tid];
        sBias[64 + tid] = b2[tid];
        sWfcS[tid] = Wfc[tid];
        sWfcS[64 + tid] = Wfc[64 + tid];
    }

    stage_chunk(Wf, sW, w, lane); // chunk 0 -> buf 0 (async)

    // j-factor registers (layer 1: h = x, fp32), stored as f32x2 pairs for pk_mul
    f32x2 hreg[2][4][4];
#pragma unroll
    for (int jg = 0; jg < 4; ++jg)
#pragma unroll
        for (int pi = 0; pi < 4; ++pi) {
            int j = jg * 16 + q2 * 8 + 2 * pi;
            hreg[0][jg][pi] = (f32x2){xb0[j * 64 + d], xb0[(j + 1) * 64 + d]};
            hreg[1][jg][pi] = (f32x2){xb1[j * 64 + d], xb1[(j + 1) * 64 + d]};
        }

    f32x16 acc0, acc1; // acc0: b0, acc1: b1 (32 o-rows = this wave's otile)
#pragma unroll
    for (int i = 0; i < 16; ++i) { acc0[i] = 0.0f; acc1[i] = 0.0f; }

    float contrib0 = 0.0f, contrib1 = 0.0f;
    float xvA0 = xb0[d], xvB0 = xb0[64 + d]; // i-rows 0,1 for b0
    float xvA1 = xb1[d], xvB1 = xb1[64 + d]; // i-rows 0,1 for b1

    auto epilogue = [&](int l) {
#pragma unroll
        for (int b = 0; b < 2; ++b) {
            const f32x16 a = b ? acc1 : acc0;
#pragma unroll
            for (int r = 0; r < 16; ++r) {
                // C/D: col = lane&31 (=d), row = (r&3) + 8*(r>>2) + 4*q2
                int o = ot * 32 + (r & 3) + 8 * (r >> 2) + 4 * q2;
                float v = a[r] + sBias[l * 64 + o];
                v = fmaxf(v, 0.0f);
                if (b) contrib1 += v * sWfcS[l * 64 + o];
                else   contrib0 += v * sWfcS[l * 64 + o];
                if (l == 0) sHT[b][d * HT_STRIDE + o] = f2bf(v);
            }
        }
    };

    for (int c = 0; c < 64; ++c) {
        __syncthreads(); // drains stage(c); orders compute(c-1) vs stage(c+1)
        if (c < 63) stage_chunk(Wf + (c + 1) * CHUNK_ELEMS,
                                sW + ((c + 1) & 1) * CHUNK_ELEMS, w, lane);
        if (c == 32) { // layer boundary: cross-wave h handoff
            epilogue(0); // writes sHT
            __syncthreads();
#pragma unroll
            for (int b = 0; b < 2; ++b)
#pragma unroll
                for (int jg = 0; jg < 4; ++jg) {
                    short8 h8 = *(const short8*)&sHT[b][d * HT_STRIDE + jg * 16 + q2 * 8];
#pragma unroll
                    for (int pi = 0; pi < 4; ++pi)
                        hreg[b][jg][pi] = (f32x2){bf2f((unsigned short)h8[2 * pi]),
                                                  bf2f((unsigned short)h8[2 * pi + 1])};
                }
#pragma unroll
            for (int i = 0; i < 16; ++i) { acc0[i] = 0.0f; acc1[i] = 0.0f; }
        }

        float x00 = xvA0, x01 = xvB0, x10 = xvA1, x11 = xvB1;
        if (c < 63) { // prefetch next chunk's i-rows (i-factor is ALWAYS x)
            int i0n = ((c + 1) & 31) * 2;
            xvA0 = xb0[i0n * 64 + d];
            xvB0 = xb0[(i0n + 1) * 64 + d];
            xvA1 = xb1[i0n * 64 + d];
            xvB1 = xb1[(i0n + 1) * 64 + d];
        }
        const unsigned short* sWc = sW + (c & 1) * CHUNK_ELEMS;
#pragma unroll
        for (int k8 = 0; k8 < 8; ++k8) {
            const int jg = k8 & 3;
            const float xu0 = (k8 < 4) ? x00 : x01; // b0's x[i][d]
            const float xu1 = (k8 < 4) ? x10 : x11; // b1's x[i][d]
            const f32x2 xq0 = {xu0, xu0};
            const f32x2 xq1 = {xu1, xu1};
            u32x4 pv0, pv1;
#pragma unroll
            for (int pi = 0; pi < 4; ++pi) {
                pv0[pi] = pk2bf_rhaz(xq0 * hreg[0][jg][pi]);
                pv1[pi] = pk2bf_rhaz(xq1 * hreg[1][jg][pi]);
            }
            short8 bf0 = __builtin_bit_cast(short8, pv0);
            short8 bf1 = __builtin_bit_cast(short8, pv1);
            short8 afrag = ((const short8*)(sWc + k8 * 1024))[ot * 64 + lane];
            acc0 = __builtin_amdgcn_mfma_f32_32x32x16_bf16(afrag, bf0, acc0, 0, 0, 0);
            acc1 = __builtin_amdgcn_mfma_f32_32x32x16_bf16(afrag, bf1, acc1, 0, 0, 0);
        }
    }
    epilogue(1);

#pragma unroll
    for (int off = 32; off > 0; off >>= 1) {
        contrib0 += __shfl_down(contrib0, off, 64);
        contrib1 += __shfl_down(contrib1, off, 64);
    }
    if (lane == 0) { sRed[w][0] = contrib0; sRed[w][1] = contrib1; }
    __syncthreads();
    if (tid < 2)
        out[bb * 2 + tid] = sRed[0][tid] + sRed[1][tid] + sRed[2][tid] + sRed[3][tid] + bfc[0];
}

extern "C" void kernel_launch(void* const* d_in, const int* in_sizes, int n_in,
                              void* d_out, int out_size, void* d_ws, size_t ws_size,
                              hipStream_t stream) {
    const float* x = (const float*)d_in[0];
    const float* W1 = (const float*)d_in[1];
    const float* b1 = (const float*)d_in[2];
    const float* W2 = (const float*)d_in[3];
    const float* b2 = (const float*)d_in[4];
    const float* Wfc = (const float*)d_in[5];
    const float* bfc = (const float*)d_in[6];
    float* out = (float*)d_out;

    unsigned short* Wf = (unsigned short*)d_ws; // 2 * 262144 bf16 = 1 MB

    prepack_kernel<<<256, 256, 0, stream>>>(W1, W2, Wf);
    cin_kernel<<<512, 256, 0, stream>>>(x, Wf, b1, b2, Wfc, bfc, out);
}

// Round 6
// 137.784 us; speedup vs baseline: 1.2666x; 1.2666x over previous
//
#include <hip/hip_runtime.h>

typedef short s16x4 __attribute__((ext_vector_type(4)));
typedef short s16x8 __attribute__((ext_vector_type(8)));
typedef float f32x2 __attribute__((ext_vector_type(2)));
typedef float f32x16 __attribute__((ext_vector_type(16)));
typedef unsigned int u32x4 __attribute__((ext_vector_type(4)));

#define HT_STRIDE 72  // bf16 row stride: 144 B = 9*16 -> 16B-aligned b128 rows

__device__ __forceinline__ unsigned short f2bf(float f) {
    unsigned int u = __float_as_uint(f);
    u += 0x7fffu + ((u >> 16) & 1u);
    return (unsigned short)(u >> 16);
}
__device__ __forceinline__ float bf2f(unsigned short h) {
    return __uint_as_float(((unsigned int)h) << 16);
}
__device__ __forceinline__ unsigned int pk2bf_rne(float lo, float hi) {
    unsigned int a = __float_as_uint(lo);
    a += 0x7fffu + ((a >> 16) & 1u);
    unsigned int b = __float_as_uint(hi);
    b += 0x7fffu + ((b >> 16) & 1u);
    return (a >> 16) | (b & 0xffff0000u);
}

// Factorization: T_l[(o,j),d] = sum_i W_l[o, i*64+j] * x[i,d]  (GEMM, K=i=64)
// A-frag prepack for 32x32x16: rows m = j_local (j = jt*32 + m), k = i.
// Wp frag index F = ((l*64+o)*2+jt)*4+ks ; value[lane][t] =
//   bf16( W_l[o][ (16*ks + 8*(lane>>5) + t)*64 + jt*32 + (lane&31) ] )
__global__ __launch_bounds__(256) void prepack_kernel(const float* __restrict__ W1,
                                                      const float* __restrict__ W2,
                                                      unsigned short* __restrict__ Wp) {
    int tid = blockIdx.x * 256 + threadIdx.x; // 0..65535, one 16B frag slice each
    int lane = tid & 63;
    int ks = (tid >> 6) & 3;
    int jt = (tid >> 8) & 1;
    int o = (tid >> 9) & 63;
    int l = tid >> 15;
    int q2 = lane >> 5;
    int n31 = lane & 31;
    const float* W = l ? W2 : W1;
    const float* base = W + o * 4096 + jt * 32 + n31;
    int i0 = 16 * ks + 8 * q2;
    float v[8];
#pragma unroll
    for (int t = 0; t < 8; ++t) v[t] = base[(i0 + t) * 64];
    u32x4 pv;
    pv[0] = pk2bf_rne(v[0], v[1]);
    pv[1] = pk2bf_rne(v[2], v[3]);
    pv[2] = pk2bf_rne(v[4], v[5]);
    pv[3] = pk2bf_rne(v[6], v[7]);
    ((u32x4*)Wp)[tid] = pv;
}

// Block = 2 batch elems, 4 waves. Wave w: b_loc = w&1, oh = w>>1 (o-parity class).
// Wave covers both d-halves (2 n-tiles) -> each A-frag feeds 2 MFMAs.
// MFMA B-operand (k = i) is ALWAYS x (register-resident for the whole kernel);
// only the consume weights (j-factor: x, then h1) switch per layer.
// A-frags stream straight from L2 (Wp = 1 MB, resident) with 1-iter prefetch.
__global__ __launch_bounds__(256, 2) void cin_kernel(const float* __restrict__ x,
                                                     const unsigned short* __restrict__ Wp,
                                                     const float* __restrict__ b1,
                                                     const float* __restrict__ b2,
                                                     const float* __restrict__ Wfc,
                                                     const float* __restrict__ bfc,
                                                     float* __restrict__ out) {
    // sH[l][b][d*72 + j]: layer-l j-factor source (l=0: x, l=1: h1), bf16 transposed
    __shared__ __align__(16) unsigned short sH[2][2][64 * HT_STRIDE]; // 36.9 KB
    __shared__ float sBias[128], sWfc[128], sRed[4];

    const int tid = threadIdx.x;
    const int w = tid >> 6;
    const int lane = tid & 63;
    const int q2 = lane >> 5;
    const int n31 = lane & 31;
    const int b_loc = w & 1;
    const int oh = w >> 1;
    const int bb = blockIdx.x;

    // ---- stage x for both b's: coalesced float4 reads -> transposed bf16 LDS ----
#pragma unroll
    for (int bl = 0; bl < 2; ++bl) {
        const float4* xb4 = (const float4*)(x + (bb * 2 + bl) * 4096);
#pragma unroll
        for (int rr = 0; rr < 4; ++rr) {
            int e4 = rr * 256 + tid;
            float4 v = xb4[e4];
            int e = e4 << 2;
            int f = e >> 6;     // field index (i / j)
            int d0 = e & 63;    // d-index
            sH[0][bl][(d0 + 0) * HT_STRIDE + f] = f2bf(v.x);
            sH[0][bl][(d0 + 1) * HT_STRIDE + f] = f2bf(v.y);
            sH[0][bl][(d0 + 2) * HT_STRIDE + f] = f2bf(v.z);
            sH[0][bl][(d0 + 3) * HT_STRIDE + f] = f2bf(v.w);
        }
    }
    if (tid < 128) {
        sBias[tid] = (tid < 64) ? b1[tid] : b2[tid - 64];
        sWfc[tid] = Wfc[tid];
    }
    __syncthreads();

    const f32x16 zz = {};
    float contrib = 0.0f;
    const s16x8* WpS8 = (const s16x8*)Wp;

    // ---- MFMA B-frags: B[k=i][n=d] = x[i,d] — fixed for BOTH layers ----
    s16x8 bfr[2][4]; // [nt][ks]
#pragma unroll
    for (int nt = 0; nt < 2; ++nt) {
        const int d = nt * 32 + n31;
#pragma unroll
        for (int ks = 0; ks < 4; ++ks)
            bfr[nt][ks] = *(const s16x8*)&sH[0][b_loc][d * HT_STRIDE + 16 * ks + 8 * q2];
    }

    for (int l = 0; l < 2; ++l) {
        if (l) __syncthreads(); // h1 writes from all waves complete

        // ---- per-layer consume weights (j-factor) from sH[l][b_loc] ----
        const unsigned short* hsrc = sH[l][b_loc];
        f32x2 cw[2][2][8];  // [nt][jt][pair], acc regs r=2p,2p+1
#pragma unroll
        for (int nt = 0; nt < 2; ++nt) {
            const int d = nt * 32 + n31;
#pragma unroll
            for (int jt = 0; jt < 2; ++jt)
#pragma unroll
                for (int m = 0; m < 4; ++m) {
                    // acc rows r=4m..4m+3 -> j = jt*32 + 4*q2 + 8*m + (0..3)
                    s16x4 hv = *(const s16x4*)&hsrc[d * HT_STRIDE + jt * 32 + 4 * q2 + 8 * m];
                    cw[nt][jt][2 * m] = (f32x2){bf2f((unsigned short)hv[0]),
                                                bf2f((unsigned short)hv[1])};
                    cw[nt][jt][2 * m + 1] = (f32x2){bf2f((unsigned short)hv[2]),
                                                    bf2f((unsigned short)hv[3])};
                }
        }

        // ---- main loop: it = (oc, jt); o = 2*oc + oh ----
        s16x8 Areg[2][4];
        {
            const int F0 = (l * 128 + 2 * oh) * 4; // o=oh, jt=0
            const s16x8* p = WpS8 + F0 * 64 + lane;
#pragma unroll
            for (int ks = 0; ks < 4; ++ks) Areg[0][ks] = p[ks * 64];
        }
        f32x2 hp[2];

#pragma unroll 2
        for (int it = 0; it < 64; ++it) {
            const int oc = it >> 1, jt = it & 1;
            const int o = 2 * oc + oh;
            if (it < 63) { // prefetch next (oc,jt) A-frags from L2
                const int itn = it + 1;
                const int on = 2 * (itn >> 1) + oh;
                const int Fn = (l * 128 + 2 * on + (itn & 1)) * 4;
                const s16x8* p = WpS8 + Fn * 64 + lane;
#pragma unroll
                for (int ks = 0; ks < 4; ++ks) Areg[(it + 1) & 1][ks] = p[ks * 64];
            }
            const s16x8* A = Areg[it & 1];

            f32x16 a0 = __builtin_amdgcn_mfma_f32_32x32x16_bf16(A[0], bfr[0][0], zz, 0, 0, 0);
            f32x16 a1 = __builtin_amdgcn_mfma_f32_32x32x16_bf16(A[0], bfr[1][0], zz, 0, 0, 0);
#pragma unroll
            for (int ks = 1; ks < 4; ++ks) {
                a0 = __builtin_amdgcn_mfma_f32_32x32x16_bf16(A[ks], bfr[0][ks], a0, 0, 0, 0);
                a1 = __builtin_amdgcn_mfma_f32_32x32x16_bf16(A[ks], bfr[1][ks], a1, 0, 0, 0);
            }

            // consume T-tile: weighted column-sum over its 32 rows (j's)
#pragma unroll
            for (int nt = 0; nt < 2; ++nt) {
                const f32x2* a2 = nt ? (const f32x2*)&a1 : (const f32x2*)&a0;
                f32x2 s = a2[0] * cw[nt][jt][0];
#pragma unroll
                for (int p = 1; p < 8; ++p) s += a2[p] * cw[nt][jt][p];
                if (jt == 0) {
                    hp[nt] = s;
                } else {
                    f32x2 t2 = hp[nt] + s;
                    float hsum = t2.x + t2.y;
                    hsum += __shfl_xor(hsum, 32, 64); // partner q2-half rows
                    float v = fmaxf(hsum + sBias[l * 64 + o], 0.0f);
                    contrib += v * sWfc[l * 64 + o];
                    if (l == 0) // h1 handoff (both q2 halves write identical bits)
                        sH[1][b_loc][(nt * 32 + n31) * HT_STRIDE + o] = f2bf(v);
                }
            }
        }
    }

    // each (o,d) accumulated by both q2 halves -> halve at the end
    contrib *= 0.5f;
#pragma unroll
    for (int off = 32; off > 0; off >>= 1)
        contrib += __shfl_down(contrib, off, 64);
    if (lane == 0) sRed[w] = contrib;
    __syncthreads();
    if (tid < 2)
        out[bb * 2 + tid] = sRed[tid] + sRed[tid + 2] + bfc[0];
}

extern "C" void kernel_launch(void* const* d_in, const int* in_sizes, int n_in,
                              void* d_out, int out_size, void* d_ws, size_t ws_size,
                              hipStream_t stream) {
    const float* x = (const float*)d_in[0];
    const float* W1 = (const float*)d_in[1];
    const float* b1 = (const float*)d_in[2];
    const float* W2 = (const float*)d_in[3];
    const float* b2 = (const float*)d_in[4];
    const float* Wfc = (const float*)d_in[5];
    const float* bfc = (const float*)d_in[6];
    float* out = (float*)d_out;

    unsigned short* Wp = (unsigned short*)d_ws; // 524288 bf16 = 1 MB prepacked W'

    prepack_kernel<<<256, 256, 0, stream>>>(W1, W2, Wp);
    cin_kernel<<<512, 256, 0, stream>>>(x, Wp, b1, b2, Wfc, bfc, out);
}